// Round 6
// baseline (570.571 us; speedup 1.0000x reference)
//
#include <hip/hip_runtime.h>
#include <hip/hip_bf16.h>
#include <stdint.h>

// Problem constants
#define B_    16
#define CIN   256
#define COUT  256
#define E_    8
#define HW    1024   // 32x32
#define PH    34     // padded H (zero halo)
#define PW    34

typedef __attribute__((ext_vector_type(8))) short  short8;
typedef __attribute__((ext_vector_type(4))) float  floatx4;

// Workspace layout (bytes):
//   [0,64)      : decisions int[16]
//   [64,16448)  : pooled float[16*256]  (SUMS; decide scales by 1/1024)
//   [XT_OFF,..) : xt bf16 [16][34][34][256]  (padded NHWC; halo zeroed by prep)
//   [WT_OFF,..) : wt bf16 [8][9][256][256]   ([e][r*3+s][co][ci])
#define XT_OFF 17408
#define XT_BYTES (B_*PH*PW*CIN*2)               // 9,469,952
#define WT_OFF (XT_OFF + XT_BYTES)

// async global->LDS, 16B per lane. LDS dest is wave-uniform base + lane*16.
__device__ __forceinline__ void gld_lds16(const void* g, void* l) {
    __builtin_amdgcn_global_load_lds(
        (const __attribute__((address_space(1))) unsigned int*)g,
        (__attribute__((address_space(3))) unsigned int*)l,
        16, 0, 0);
}

// ---------------- Kernel 1: fused prep ----------------
// bid < 128   : xpose+pool+halo.  block = (b, 32-ci slice); reads x[b, ci0:ci0+32, :]
//               (128 KB, coalesced), writes xt interior bf16 + halo zeros, and the
//               pooled sums via in-wave shuffle reduction (no atomics, no pre-zero).
// bid >= 128  : wpose.  block = (e, co); we [e][co][ci][3][3] -> wt [e][rs][co][ci] bf16.
__global__ void prep_kernel(const float* __restrict__ x, const float* __restrict__ we,
                            unsigned short* __restrict__ xt, unsigned short* __restrict__ wt,
                            float* __restrict__ pooled) {
    int bid = blockIdx.x;
    int t = threadIdx.x;
    if (bid < 128) {
        int b = bid >> 3, ci0 = (bid & 7) * 32;
        __shared__ float tileF[32][65];
        float psum[8];
        #pragma unroll
        for (int li = 0; li < 8; ++li) psum[li] = 0.0f;
        int hwl = t & 63, wv = t >> 6;         // load coords: wave wv owns ci = wv + 4*li
        int hwl2 = t >> 2, grp = t & 3;        // store coords: 64 hw x 4 ci-groups of 8
        for (int chunk = 0; chunk < 16; ++chunk) {
            #pragma unroll
            for (int li = 0; li < 8; ++li) {
                int ci = wv + li*4;
                float v = x[((size_t)b*CIN + ci0 + ci)*HW + chunk*64 + hwl];
                tileF[ci][hwl] = v;
                psum[li] += v;
            }
            __syncthreads();
            int hw = chunk*64 + hwl2;
            int h = hw >> 5, w = hw & 31;
            short8 v8;
            #pragma unroll
            for (int q = 0; q < 8; ++q) {
                __hip_bfloat16 hv = __float2bfloat16(tileF[grp*8 + q][hwl2]);
                v8[q] = *(short*)&hv;
            }
            *(short8*)&xt[(((size_t)b*PH + h + 1)*PW + (w + 1))*CIN + ci0 + grp*8] = v8;
            __syncthreads();                   // before next chunk overwrites tileF
        }
        // pool: full-wave reduce each of the 8 ci rows this wave owns
        #pragma unroll
        for (int li = 0; li < 8; ++li) {
            float s = psum[li];
            #pragma unroll
            for (int o = 32; o > 0; o >>= 1) s += __shfl_down(s, o, 64);
            if ((t & 63) == 0) pooled[b*CIN + ci0 + wv + li*4] = s;
        }
        // halo zeros for this (b, ci slice): 132 border positions x 4 ci-groups
        short8 z = {0,0,0,0,0,0,0,0};
        for (int idx = t; idx < 528; idx += 256) {
            int pos = idx >> 2, sub = idx & 3;
            int h, w;
            if (pos < 34)       { h = 0;            w = pos; }
            else if (pos < 68)  { h = 33;           w = pos - 34; }
            else if (pos < 100) { h = pos - 68 + 1; w = 0; }
            else                { h = pos - 100 + 1;w = 33; }
            *(short8*)&xt[(((size_t)b*PH + h)*PW + w)*CIN + ci0 + sub*8] = z;
        }
    } else {
        int wbid = bid - 128;
        int e = wbid >> 8, co = wbid & 255;
        __shared__ float buf[CIN*9];
        const float* src = we + ((size_t)e*COUT + co)*CIN*9;
        #pragma unroll
        for (int k = 0; k < 9; ++k) buf[t + k*256] = src[t + k*256];
        __syncthreads();
        for (int idx = t; idx < 288; idx += 256) {
            int rs = idx >> 5, grp = idx & 31;
            short8 v;
            #pragma unroll
            for (int q = 0; q < 8; ++q) {
                __hip_bfloat16 h = __float2bfloat16(buf[(grp*8 + q)*9 + rs]);
                v[q] = *(short*)&h;
            }
            *(short8*)&wt[(((size_t)e*9 + rs)*COUT + co)*CIN + grp*8] = v;
        }
    }
}

// ---------------- Kernel 2: logits + argmax -> decisions (1 block, ~3 us) ----------------
__global__ void decide_kernel(const float* __restrict__ pooled, const float* __restrict__ wc,
                              const float* __restrict__ bc, int* __restrict__ dec) {
    int t = threadIdx.x;          // 128 threads: b = t/8, e = t%8
    int b = t >> 3, e = t & 7;
    float acc = 0.0f;
    const float4* pp = (const float4*)(pooled + b*CIN);
    const float4* ww = (const float4*)(wc + e*CIN);
    #pragma unroll 4
    for (int i = 0; i < CIN/4; ++i) {
        float4 p = pp[i], w = ww[i];
        acc += p.x*w.x + p.y*w.y + p.z*w.z + p.w*w.w;
    }
    acc = acc * (1.0f/1024.0f) + bc[e];   // pooled holds sums; mean = sum/1024
    __shared__ float lg[16][8];
    lg[b][e] = acc;
    __syncthreads();
    if (e == 0) {
        float best = lg[b][0]; int bi = 0;
        #pragma unroll
        for (int j = 1; j < 8; ++j) { if (lg[b][j] > best) { best = lg[b][j]; bi = j; } }
        dec[b] = bi;
    }
}

// ---------------- Kernel 3: shift-decomposed implicit-GEMM conv + gather-write ----------------
// R0-proven loop structure (double-buffered sA, plain __syncthreads per iteration) with ONE
// change: single-buffered sB, re-staged per ci-chunk behind an lgkmcnt-fence barrier.
// LDS 50 KB -> 29.7 KB => 4 blocks/CU (16 waves, 4/SIMD; VGPR ~116, NO launch_bounds cap).
// Mechanism: more co-resident independent blocks to hide the per-iteration barrier drain.
// grid: x = mt*8+nt (16 tiles of the 256x1024 output), y = b (16), z = e (8); 256 threads
__global__ void conv_kernel(
    const unsigned short* __restrict__ xt, const unsigned short* __restrict__ wt,
    const float* __restrict__ be, const int* __restrict__ dec,
    float* __restrict__ out) {

    int tile = blockIdx.x;
    int b = blockIdx.y;
    int e = blockIdx.z;
    int mt = tile >> 3, nt = tile & 7;

    int dcs[16];
    #pragma unroll
    for (int i = 0; i < 16; ++i) dcs[i] = dec[i];
    bool active = false;
    #pragma unroll
    for (int i = 0; i < 16; ++i) active |= (dcs[i] == e);
    if (!active) return;   // uniform across block

    // Chunk-addressed LDS (16 B chunks), XOR-swizzled: global chunk (row, g)
    // lives at LDS chunk row*4 + (g ^ ((row>>1)&3)).  Involutive.
    // sA[2]: 512 chunks each (A tile 128 co x 4 ci-chunks), 8 KB each -> 16 KB.
    // sB   : 832 chunks (816 live: 6x34 halo rows x 4 ci-chunks), 13 KB, SINGLE buffer.
    // Total 29.7 KB -> 4 blocks/CU.
    __shared__ __align__(16) unsigned short sA[2][512*8];
    __shared__ __align__(16) unsigned short sB[832*8];

    int t = threadIdx.x;
    int wave = t >> 6, lane = t & 63;
    int wm = wave >> 1, wn = wave & 1;     // 2x2 wave grid, 64x64 per wave
    int kg = lane >> 4, ln = lane & 15;

    int ph0 = nt * 4;       // padded halo start row
    int co0 = mt * 128;

    floatx4 acc[4][4];
    #pragma unroll
    for (int i = 0; i < 4; ++i)
        #pragma unroll
        for (int j = 0; j < 4; ++j) acc[i][j] = (floatx4)0.0f;

    const unsigned short* xb = xt + ((size_t)b*PH + ph0)*PW*CIN;   // halo base (6x34 rows)
    const unsigned short* wb = wt + (size_t)e*9*COUT*CIN + (size_t)co0*CIN;

    auto stageA = [&](int ck, int sh, int buf) {
        const unsigned short* wsrc = wb + (size_t)sh*COUT*CIN + ck*32;
        #pragma unroll
        for (int k = 0; k < 2; ++k) {
            int c = t + k*256;
            int row = c >> 2, gs = c & 3;
            int g = gs ^ ((row >> 1) & 3);
            gld_lds16(wsrc + (size_t)row*CIN + g*8, &sA[buf][c*8]);
        }
    };
    auto stageB = [&](int ck) {
        const unsigned short* xsrc = xb + ck*32;
        #pragma unroll
        for (int k = 0; k < 3; ++k) {
            int c = t + k*256;
            int rB = c >> 2, gs = c & 3;
            int g = gs ^ ((rB >> 1) & 3);
            gld_lds16(xsrc + (size_t)rB*CIN + g*8, &sB[c*8]);
        }
        if (t < 64) {                     // wave 0: chunks 768..831 (816..831 dead-clamped)
            int c = t + 768;
            int cc = c < 816 ? c : 815;
            int rB = cc >> 2, gs = cc & 3;
            int g = gs ^ ((rB >> 1) & 3);
            gld_lds16(xsrc + (size_t)rB*CIN + g*8, &sB[c*8]);
        }
    };

    // frag-read helpers (swizzled)
    short8 a[4], bv[4];
    auto readA = [&](int ab) {
        #pragma unroll
        for (int im = 0; im < 4; ++im) {
            int row = wm*64 + im*16 + ln;
            int cL = row*4 + (kg ^ ((row >> 1) & 3));
            a[im] = *(const short8*)(&sA[ab][cL*8]);
        }
    };
    auto readB = [&](int r, int s) {
        #pragma unroll
        for (int in = 0; in < 4; ++in) {
            int n  = wn*64 + in*16 + ln;
            int hl = n >> 5, wl = n & 31;
            int rB = (hl + r)*34 + (wl + s);
            int cL = rB*4 + (kg ^ ((rB >> 1) & 3));
            bv[in] = *(const short8*)(&sB[cL*8]);
        }
    };

    // ---- prologue: stage iteration 0 ----
    stageB(0);
    stageA(0, 0, 0);
    __syncthreads();

    // ---- main loop: it = ck*9+sh; sA parity = it&1; sB single-buffered ----
    for (int ck = 0; ck < 8; ++ck) {
        for (int sh = 0; sh < 9; ++sh) {
            int it = ck*9 + sh;
            int ab = it & 1;
            int r = sh / 3, s = sh - r*3;

            if (sh < 8) {
                // steady: prefetch next shift's A, read frags, MFMA, barrier
                stageA(ck, sh + 1, ab ^ 1);
                readA(ab);
                readB(r, s);
                #pragma unroll
                for (int im = 0; im < 4; ++im)
                    #pragma unroll
                    for (int in = 0; in < 4; ++in)
                        acc[im][in] = __builtin_amdgcn_mfma_f32_16x16x32_bf16(bv[in], a[im], acc[im][in], 0, 0, 0);
                __syncthreads();   // frag reads done + prefetch DMA drained
            } else {
                // ck boundary: consume B frags, fence ALL waves' B reads, then
                // overwrite sB with the next ci-chunk (drained by the end barrier).
                readB(r, s);
                if (ck < 7) {
                    asm volatile("s_waitcnt lgkmcnt(0)" ::: "memory");
                    __builtin_amdgcn_s_barrier();
                    stageB(ck + 1);
                    stageA(ck + 1, 0, ab ^ 1);
                }
                readA(ab);
                #pragma unroll
                for (int im = 0; im < 4; ++im)
                    #pragma unroll
                    for (int in = 0; in < 4; ++in)
                        acc[im][in] = __builtin_amdgcn_mfma_f32_16x16x32_bf16(bv[in], a[im], acc[im][in], 0, 0, 0);
                if (ck < 7) __syncthreads();   // drains stageB/stageA DMA (vmcnt 0)
            }
        }
    }

    // ---- epilogue: bias + relu.  Layout: col(ln)=co, row(kg*4+rg)=hw ----
    float bias[4];
    #pragma unroll
    for (int im = 0; im < 4; ++im)
        bias[im] = be[e*COUT + co0 + wm*64 + im*16 + ln];
    #pragma unroll
    for (int im = 0; im < 4; ++im)
        #pragma unroll
        for (int in = 0; in < 4; ++in)
            #pragma unroll
            for (int rg = 0; rg < 4; ++rg) {
                float v = acc[im][in][rg] + bias[im];
                acc[im][in][rg] = v > 0.0f ? v : 0.0f;
            }

    // ---- write to every output slot i with dec[i]==e: float4 stores along hw ----
    for (int i = 0; i < 16; ++i) {
        if (dcs[i] != e) continue;
        float* ob = out + (size_t)(i*16 + b)*COUT*HW;
        #pragma unroll
        for (int im = 0; im < 4; ++im) {
            int co = co0 + wm*64 + im*16 + ln;
            float* orow = ob + (size_t)co*HW + nt*128 + wn*64 + kg*4;
            #pragma unroll
            for (int in = 0; in < 4; ++in)
                *(floatx4*)(orow + in*16) = acc[im][in];
        }
    }
}

extern "C" void kernel_launch(void* const* d_in, const int* in_sizes, int n_in,
                              void* d_out, int out_size, void* d_ws, size_t ws_size,
                              hipStream_t stream) {
    const float* x  = (const float*)d_in[0];
    const float* wc = (const float*)d_in[1];
    const float* bc = (const float*)d_in[2];
    const float* we = (const float*)d_in[3];
    const float* be = (const float*)d_in[4];
    float* out = (float*)d_out;

    char* ws = (char*)d_ws;
    int*   dec    = (int*)ws;
    float* pooled = (float*)(ws + 64);
    unsigned short* xt = (unsigned short*)(ws + XT_OFF);
    unsigned short* wt = (unsigned short*)(ws + WT_OFF);

    // Three dispatches.  No memset: prep writes pooled/xt/wt fully; dec written by decide.
    prep_kernel  <<<2176, 256, 0, stream>>>(x, we, xt, wt, pooled);
    decide_kernel<<<1, 128, 0, stream>>>(pooled, wc, bc, dec);
    conv_kernel  <<<dim3(16, 16, 8), 256, 0, stream>>>(xt, wt, be, dec, out);
}

// Round 7
// 464.016 us; speedup vs baseline: 1.2296x; 1.2296x over previous
//
#include <hip/hip_runtime.h>
#include <hip/hip_bf16.h>
#include <stdint.h>

// Problem constants
#define B_    16
#define CIN   256
#define COUT  256
#define E_    8
#define HW    1024   // 32x32
#define PH    34     // padded H (zero halo)
#define PW    34

typedef __attribute__((ext_vector_type(8))) short  short8;
typedef __attribute__((ext_vector_type(4))) float  floatx4;

// Workspace layout (bytes):
//   [0,64)      : decisions int[16]
//   [64,16448)  : pooled float[16*256]  (SUMS; decide scales by 1/1024)
//   [XT_OFF,..) : xt bf16 [16][34][34][256]  (padded NHWC; halo zeroed by prep)
//   [WT_OFF,..) : wt bf16 [8][9][256][256]   ([e][r*3+s][co][ci])
#define XT_OFF 17408
#define XT_BYTES (B_*PH*PW*CIN*2)               // 9,469,952
#define WT_OFF (XT_OFF + XT_BYTES)

// async global->LDS, 16B per lane. LDS dest is wave-uniform base + lane*16.
__device__ __forceinline__ void gld_lds16(const void* g, void* l) {
    __builtin_amdgcn_global_load_lds(
        (const __attribute__((address_space(1))) unsigned int*)g,
        (__attribute__((address_space(3))) unsigned int*)l,
        16, 0, 0);
}

// ---------------- Kernel 1: fused prep ----------------
// bid < 128   : xpose+pool+halo.  block = (b, 32-ci slice); reads x[b, ci0:ci0+32, :]
//               (128 KB, coalesced), writes xt interior bf16 + halo zeros, and the
//               pooled sums via in-wave shuffle reduction (no atomics, no pre-zero).
// bid >= 128  : wpose.  block = (e, co); we [e][co][ci][3][3] -> wt [e][rs][co][ci] bf16.
__global__ __launch_bounds__(256) void prep_kernel(
    const float* __restrict__ x, const float* __restrict__ we,
    unsigned short* __restrict__ xt, unsigned short* __restrict__ wt,
    float* __restrict__ pooled) {
    int bid = blockIdx.x;
    int t = threadIdx.x;
    if (bid < 128) {
        int b = bid >> 3, ci0 = (bid & 7) * 32;
        __shared__ float tileF[32][65];
        float psum[8];
        #pragma unroll
        for (int li = 0; li < 8; ++li) psum[li] = 0.0f;
        int hwl = t & 63, wv = t >> 6;         // load coords: wave wv owns ci = wv + 4*li
        int hwl2 = t >> 2, grp = t & 3;        // store coords: 64 hw x 4 ci-groups of 8
        for (int chunk = 0; chunk < 16; ++chunk) {
            #pragma unroll
            for (int li = 0; li < 8; ++li) {
                int ci = wv + li*4;
                float v = x[((size_t)b*CIN + ci0 + ci)*HW + chunk*64 + hwl];
                tileF[ci][hwl] = v;
                psum[li] += v;
            }
            __syncthreads();
            int hw = chunk*64 + hwl2;
            int h = hw >> 5, w = hw & 31;
            short8 v8;
            #pragma unroll
            for (int q = 0; q < 8; ++q) {
                __hip_bfloat16 hv = __float2bfloat16(tileF[grp*8 + q][hwl2]);
                v8[q] = *(short*)&hv;
            }
            *(short8*)&xt[(((size_t)b*PH + h + 1)*PW + (w + 1))*CIN + ci0 + grp*8] = v8;
            __syncthreads();                   // before next chunk overwrites tileF
        }
        // pool: full-wave reduce each of the 8 ci rows this wave owns
        #pragma unroll
        for (int li = 0; li < 8; ++li) {
            float s = psum[li];
            #pragma unroll
            for (int o = 32; o > 0; o >>= 1) s += __shfl_down(s, o, 64);
            if ((t & 63) == 0) pooled[b*CIN + ci0 + wv + li*4] = s;
        }
        // halo zeros for this (b, ci slice): 132 border positions x 4 ci-groups
        short8 z = {0,0,0,0,0,0,0,0};
        for (int idx = t; idx < 528; idx += 256) {
            int pos = idx >> 2, sub = idx & 3;
            int h, w;
            if (pos < 34)       { h = 0;            w = pos; }
            else if (pos < 68)  { h = 33;           w = pos - 34; }
            else if (pos < 100) { h = pos - 68 + 1; w = 0; }
            else                { h = pos - 100 + 1;w = 33; }
            *(short8*)&xt[(((size_t)b*PH + h)*PW + w)*CIN + ci0 + sub*8] = z;
        }
    } else {
        int wbid = bid - 128;
        int e = wbid >> 8, co = wbid & 255;
        __shared__ float buf[CIN*9];
        const float* src = we + ((size_t)e*COUT + co)*CIN*9;
        #pragma unroll
        for (int k = 0; k < 9; ++k) buf[t + k*256] = src[t + k*256];
        __syncthreads();
        for (int idx = t; idx < 288; idx += 256) {
            int rs = idx >> 5, grp = idx & 31;
            short8 v;
            #pragma unroll
            for (int q = 0; q < 8; ++q) {
                __hip_bfloat16 h = __float2bfloat16(buf[(grp*8 + q)*9 + rs]);
                v[q] = *(short*)&h;
            }
            *(short8*)&wt[(((size_t)e*9 + rs)*COUT + co)*CIN + grp*8] = v;
        }
    }
}

// ---------------- Kernel 2: logits + argmax -> decisions (1 block, ~3 us) ----------------
__global__ __launch_bounds__(128) void decide_kernel(
    const float* __restrict__ pooled, const float* __restrict__ wc,
    const float* __restrict__ bc, int* __restrict__ dec) {
    int t = threadIdx.x;          // 128 threads: b = t/8, e = t%8
    int b = t >> 3, e = t & 7;
    float acc = 0.0f;
    const float4* pp = (const float4*)(pooled + b*CIN);
    const float4* ww = (const float4*)(wc + e*CIN);
    #pragma unroll 4
    for (int i = 0; i < CIN/4; ++i) {
        float4 p = pp[i], w = ww[i];
        acc += p.x*w.x + p.y*w.y + p.z*w.z + p.w*w.w;
    }
    acc = acc * (1.0f/1024.0f) + bc[e];   // pooled holds sums; mean = sum/1024
    __shared__ float lg[16][8];
    lg[b][e] = acc;
    __syncthreads();
    if (e == 0) {
        float best = lg[b][0]; int bi = 0;
        #pragma unroll
        for (int j = 1; j < 8; ++j) { if (lg[b][j] > best) { best = lg[b][j]; bi = j; } }
        dec[b] = bi;
    }
}

// ---------------- Kernel 3: shift-decomposed implicit-GEMM conv + gather-write ----------------
// R0-proven loop structure (double-buffered sA, plain __syncthreads per iteration), single-
// buffered sB (re-staged per ci-chunk behind an lgkmcnt-fence barrier).
// LDS 29.7 KB => 4 blocks/CU from LDS.  __launch_bounds__(256) WITH NO min-waves arg is
// load-bearing: it caps the assumed block size at 256 so the compiler allocates ~110 VGPRs
// (4 waves/SIMD) instead of the 64-reg spill regime (R2/R6) or the 128-pin (R3).
// grid: x = mt*8+nt (16 tiles of the 256x1024 output), y = b (16), z = e (8); 256 threads
__global__ __launch_bounds__(256) void conv_kernel(
    const unsigned short* __restrict__ xt, const unsigned short* __restrict__ wt,
    const float* __restrict__ be, const int* __restrict__ dec,
    float* __restrict__ out) {

    int tile = blockIdx.x;
    int b = blockIdx.y;
    int e = blockIdx.z;
    int mt = tile >> 3, nt = tile & 7;

    int dcs[16];
    #pragma unroll
    for (int i = 0; i < 16; ++i) dcs[i] = dec[i];
    bool active = false;
    #pragma unroll
    for (int i = 0; i < 16; ++i) active |= (dcs[i] == e);
    if (!active) return;   // uniform across block

    // Chunk-addressed LDS (16 B chunks), XOR-swizzled: global chunk (row, g)
    // lives at LDS chunk row*4 + (g ^ ((row>>1)&3)).  Involutive.
    // sA[2]: 512 chunks each (A tile 128 co x 4 ci-chunks), 8 KB each -> 16 KB.
    // sB   : 832 chunks (816 live: 6x34 halo rows x 4 ci-chunks), 13 KB, SINGLE buffer.
    // Total 29.7 KB -> 4 blocks/CU.
    __shared__ __align__(16) unsigned short sA[2][512*8];
    __shared__ __align__(16) unsigned short sB[832*8];

    int t = threadIdx.x;
    int wave = t >> 6, lane = t & 63;
    int wm = wave >> 1, wn = wave & 1;     // 2x2 wave grid, 64x64 per wave
    int kg = lane >> 4, ln = lane & 15;

    int ph0 = nt * 4;       // padded halo start row
    int co0 = mt * 128;

    floatx4 acc[4][4];
    #pragma unroll
    for (int i = 0; i < 4; ++i)
        #pragma unroll
        for (int j = 0; j < 4; ++j) acc[i][j] = (floatx4)0.0f;

    const unsigned short* xb = xt + ((size_t)b*PH + ph0)*PW*CIN;   // halo base (6x34 rows)
    const unsigned short* wb = wt + (size_t)e*9*COUT*CIN + (size_t)co0*CIN;

    auto stageA = [&](int ck, int sh, int buf) {
        const unsigned short* wsrc = wb + (size_t)sh*COUT*CIN + ck*32;
        #pragma unroll
        for (int k = 0; k < 2; ++k) {
            int c = t + k*256;
            int row = c >> 2, gs = c & 3;
            int g = gs ^ ((row >> 1) & 3);
            gld_lds16(wsrc + (size_t)row*CIN + g*8, &sA[buf][c*8]);
        }
    };
    auto stageB = [&](int ck) {
        const unsigned short* xsrc = xb + ck*32;
        #pragma unroll
        for (int k = 0; k < 3; ++k) {
            int c = t + k*256;
            int rB = c >> 2, gs = c & 3;
            int g = gs ^ ((rB >> 1) & 3);
            gld_lds16(xsrc + (size_t)rB*CIN + g*8, &sB[c*8]);
        }
        if (t < 64) {                     // wave 0: chunks 768..831 (816..831 dead-clamped)
            int c = t + 768;
            int cc = c < 816 ? c : 815;
            int rB = cc >> 2, gs = cc & 3;
            int g = gs ^ ((rB >> 1) & 3);
            gld_lds16(xsrc + (size_t)rB*CIN + g*8, &sB[c*8]);
        }
    };

    // frag-read helpers (swizzled)
    short8 a[4], bv[4];
    auto readA = [&](int ab) {
        #pragma unroll
        for (int im = 0; im < 4; ++im) {
            int row = wm*64 + im*16 + ln;
            int cL = row*4 + (kg ^ ((row >> 1) & 3));
            a[im] = *(const short8*)(&sA[ab][cL*8]);
        }
    };
    auto readB = [&](int r, int s) {
        #pragma unroll
        for (int in = 0; in < 4; ++in) {
            int n  = wn*64 + in*16 + ln;
            int hl = n >> 5, wl = n & 31;
            int rB = (hl + r)*34 + (wl + s);
            int cL = rB*4 + (kg ^ ((rB >> 1) & 3));
            bv[in] = *(const short8*)(&sB[cL*8]);
        }
    };

    // ---- prologue: stage iteration 0 ----
    stageB(0);
    stageA(0, 0, 0);
    __syncthreads();

    // ---- main loop: it = ck*9+sh; sA parity = it&1; sB single-buffered ----
    for (int ck = 0; ck < 8; ++ck) {
        for (int sh = 0; sh < 9; ++sh) {
            int it = ck*9 + sh;
            int ab = it & 1;
            int r = sh / 3, s = sh - r*3;

            if (sh < 8) {
                // steady: prefetch next shift's A, read frags, MFMA, barrier
                stageA(ck, sh + 1, ab ^ 1);
                readA(ab);
                readB(r, s);
                #pragma unroll
                for (int im = 0; im < 4; ++im)
                    #pragma unroll
                    for (int in = 0; in < 4; ++in)
                        acc[im][in] = __builtin_amdgcn_mfma_f32_16x16x32_bf16(bv[in], a[im], acc[im][in], 0, 0, 0);
                __syncthreads();   // frag reads done + prefetch DMA drained
            } else {
                // ck boundary: consume B frags, fence ALL waves' B reads, then
                // overwrite sB with the next ci-chunk (drained by the end barrier).
                readB(r, s);
                if (ck < 7) {
                    asm volatile("s_waitcnt lgkmcnt(0)" ::: "memory");
                    __builtin_amdgcn_s_barrier();
                    stageB(ck + 1);
                    stageA(ck + 1, 0, ab ^ 1);
                }
                readA(ab);
                #pragma unroll
                for (int im = 0; im < 4; ++im)
                    #pragma unroll
                    for (int in = 0; in < 4; ++in)
                        acc[im][in] = __builtin_amdgcn_mfma_f32_16x16x32_bf16(bv[in], a[im], acc[im][in], 0, 0, 0);
                if (ck < 7) __syncthreads();   // drains stageB/stageA DMA (vmcnt 0)
            }
        }
    }

    // ---- epilogue: bias + relu.  Layout: col(ln)=co, row(kg*4+rg)=hw ----
    float bias[4];
    #pragma unroll
    for (int im = 0; im < 4; ++im)
        bias[im] = be[e*COUT + co0 + wm*64 + im*16 + ln];
    #pragma unroll
    for (int im = 0; im < 4; ++im)
        #pragma unroll
        for (int in = 0; in < 4; ++in)
            #pragma unroll
            for (int rg = 0; rg < 4; ++rg) {
                float v = acc[im][in][rg] + bias[im];
                acc[im][in][rg] = v > 0.0f ? v : 0.0f;
            }

    // ---- write to every output slot i with dec[i]==e: float4 stores along hw ----
    for (int i = 0; i < 16; ++i) {
        if (dcs[i] != e) continue;
        float* ob = out + (size_t)(i*16 + b)*COUT*HW;
        #pragma unroll
        for (int im = 0; im < 4; ++im) {
            int co = co0 + wm*64 + im*16 + ln;
            float* orow = ob + (size_t)co*HW + nt*128 + wn*64 + kg*4;
            #pragma unroll
            for (int in = 0; in < 4; ++in)
                *(floatx4*)(orow + in*16) = acc[im][in];
        }
    }
}

extern "C" void kernel_launch(void* const* d_in, const int* in_sizes, int n_in,
                              void* d_out, int out_size, void* d_ws, size_t ws_size,
                              hipStream_t stream) {
    const float* x  = (const float*)d_in[0];
    const float* wc = (const float*)d_in[1];
    const float* bc = (const float*)d_in[2];
    const float* we = (const float*)d_in[3];
    const float* be = (const float*)d_in[4];
    float* out = (float*)d_out;

    char* ws = (char*)d_ws;
    int*   dec    = (int*)ws;
    float* pooled = (float*)(ws + 64);
    unsigned short* xt = (unsigned short*)(ws + XT_OFF);
    unsigned short* wt = (unsigned short*)(ws + WT_OFF);

    // Three dispatches.  No memset: prep writes pooled/xt/wt fully; dec written by decide.
    prep_kernel  <<<2176, 256, 0, stream>>>(x, we, xt, wt, pooled);
    decide_kernel<<<1, 128, 0, stream>>>(pooled, wc, bc, dec);
    conv_kernel  <<<dim3(16, 16, 8), 256, 0, stream>>>(xt, wt, be, dec, out);
}

// Round 8
// 434.745 us; speedup vs baseline: 1.3124x; 1.0673x over previous
//
#include <hip/hip_runtime.h>
#include <hip/hip_bf16.h>
#include <stdint.h>

// Problem constants
#define B_    16
#define CIN   256
#define COUT  256
#define E_    8
#define HW    1024   // 32x32
#define PH    34     // padded H (zero halo)
#define PW    34

typedef __attribute__((ext_vector_type(8))) short  short8;
typedef __attribute__((ext_vector_type(4))) float  floatx4;

// Workspace layout (bytes):
//   [0,64)      : decisions int[16]
//   [64,16448)  : pooled float[16*256]  (SUMS; decide scales by 1/1024)
//   [XT_OFF,..) : xt bf16 [16][34][34][256]  (padded NHWC; halo zeroed by prep)
//   [WT_OFF,..) : wt bf16 [8][9][256][256]   ([e][r*3+s][co][ci])
#define XT_OFF 17408
#define XT_BYTES (B_*PH*PW*CIN*2)               // 9,469,952
#define WT_OFF (XT_OFF + XT_BYTES)

// async global->LDS, 16B per lane. LDS dest is wave-uniform base + lane*16.
__device__ __forceinline__ void gld_lds16(const void* g, void* l) {
    __builtin_amdgcn_global_load_lds(
        (const __attribute__((address_space(1))) unsigned int*)g,
        (__attribute__((address_space(3))) unsigned int*)l,
        16, 0, 0);
}

// ---------------- Kernel 1: fused prep ----------------
// bid < 128   : xpose+pool+halo.  block = (b, 32-ci slice).
// bid >= 128  : wpose.  block = (e, co); we [e][co][ci][3][3] -> wt [e][rs][co][ci] bf16.
__global__ __launch_bounds__(256) void prep_kernel(
    const float* __restrict__ x, const float* __restrict__ we,
    unsigned short* __restrict__ xt, unsigned short* __restrict__ wt,
    float* __restrict__ pooled) {
    int bid = blockIdx.x;
    int t = threadIdx.x;
    if (bid < 128) {
        int b = bid >> 3, ci0 = (bid & 7) * 32;
        __shared__ float tileF[32][65];
        float psum[8];
        #pragma unroll
        for (int li = 0; li < 8; ++li) psum[li] = 0.0f;
        int hwl = t & 63, wv = t >> 6;
        int hwl2 = t >> 2, grp = t & 3;
        for (int chunk = 0; chunk < 16; ++chunk) {
            #pragma unroll
            for (int li = 0; li < 8; ++li) {
                int ci = wv + li*4;
                float v = x[((size_t)b*CIN + ci0 + ci)*HW + chunk*64 + hwl];
                tileF[ci][hwl] = v;
                psum[li] += v;
            }
            __syncthreads();
            int hw = chunk*64 + hwl2;
            int h = hw >> 5, w = hw & 31;
            short8 v8;
            #pragma unroll
            for (int q = 0; q < 8; ++q) {
                __hip_bfloat16 hv = __float2bfloat16(tileF[grp*8 + q][hwl2]);
                v8[q] = *(short*)&hv;
            }
            *(short8*)&xt[(((size_t)b*PH + h + 1)*PW + (w + 1))*CIN + ci0 + grp*8] = v8;
            __syncthreads();
        }
        #pragma unroll
        for (int li = 0; li < 8; ++li) {
            float s = psum[li];
            #pragma unroll
            for (int o = 32; o > 0; o >>= 1) s += __shfl_down(s, o, 64);
            if ((t & 63) == 0) pooled[b*CIN + ci0 + wv + li*4] = s;
        }
        short8 z = {0,0,0,0,0,0,0,0};
        for (int idx = t; idx < 528; idx += 256) {
            int pos = idx >> 2, sub = idx & 3;
            int h, w;
            if (pos < 34)       { h = 0;            w = pos; }
            else if (pos < 68)  { h = 33;           w = pos - 34; }
            else if (pos < 100) { h = pos - 68 + 1; w = 0; }
            else                { h = pos - 100 + 1;w = 33; }
            *(short8*)&xt[(((size_t)b*PH + h)*PW + w)*CIN + ci0 + sub*8] = z;
        }
    } else {
        int wbid = bid - 128;
        int e = wbid >> 8, co = wbid & 255;
        __shared__ float buf[CIN*9];
        const float* src = we + ((size_t)e*COUT + co)*CIN*9;
        #pragma unroll
        for (int k = 0; k < 9; ++k) buf[t + k*256] = src[t + k*256];
        __syncthreads();
        for (int idx = t; idx < 288; idx += 256) {
            int rs = idx >> 5, grp = idx & 31;
            short8 v;
            #pragma unroll
            for (int q = 0; q < 8; ++q) {
                __hip_bfloat16 h = __float2bfloat16(buf[(grp*8 + q)*9 + rs]);
                v[q] = *(short*)&h;
            }
            *(short8*)&wt[(((size_t)e*9 + rs)*COUT + co)*CIN + grp*8] = v;
        }
    }
}

// ---------------- Kernel 2: logits + argmax -> decisions (1 block) ----------------
__global__ __launch_bounds__(128) void decide_kernel(
    const float* __restrict__ pooled, const float* __restrict__ wc,
    const float* __restrict__ bc, int* __restrict__ dec) {
    int t = threadIdx.x;
    int b = t >> 3, e = t & 7;
    float acc = 0.0f;
    const float4* pp = (const float4*)(pooled + b*CIN);
    const float4* ww = (const float4*)(wc + e*CIN);
    #pragma unroll 4
    for (int i = 0; i < CIN/4; ++i) {
        float4 p = pp[i], w = ww[i];
        acc += p.x*w.x + p.y*w.y + p.z*w.z + p.w*w.w;
    }
    acc = acc * (1.0f/1024.0f) + bc[e];
    __shared__ float lg[16][8];
    lg[b][e] = acc;
    __syncthreads();
    if (e == 0) {
        float best = lg[b][0]; int bi = 0;
        #pragma unroll
        for (int j = 1; j < 8; ++j) { if (lg[b][j] > best) { best = lg[b][j]; bi = j; } }
        dec[b] = bi;
    }
}

// ---------------- Kernel 3: shift-decomposed implicit-GEMM conv + gather-write ----------------
// R7-proven skeleton with two changes:
//  (1) BK=64: 36 iterations instead of 72 -> half the barrier-drain events, 3 (not 7)
//      ck-boundary fences.  LDS 60 KB; occupancy unchanged (reg-capped at 2 blocks/CU).
//  (2) XCD-aware 1D-grid swizzle: gid%8 = XCD -> wid chunk of 256 contiguous work items,
//      decoded so each XCD covers 2 b-values x all e x all tiles (wt/xt panels L2-resident,
//      no idle-expert imbalance).
// XOR swizzle generalized to 8 ci-chunks/row: LDS chunk (row, gl) holds source chunk
// gl ^ (row&7); readers apply the same XOR (involutive).  16-lane frag reads spread
// across all 8 bank-quads (2-way = free).
__global__ __launch_bounds__(256) void conv_kernel(
    const unsigned short* __restrict__ xt, const unsigned short* __restrict__ wt,
    const float* __restrict__ be, const int* __restrict__ dec,
    float* __restrict__ out) {

    int gid = blockIdx.x;                       // 0..2047
    int wid = (gid & 7) * 256 + (gid >> 3);     // XCD-chunked bijective swizzle (2048%8==0)
    int tile = wid & 15;
    int g_   = wid >> 4;                        // 0..127
    int e = g_ & 7;
    int b = g_ >> 3;
    int mt = tile >> 3, nt = tile & 7;

    int dcs[16];
    #pragma unroll
    for (int i = 0; i < 16; ++i) dcs[i] = dec[i];
    bool active = false;
    #pragma unroll
    for (int i = 0; i < 16; ++i) active |= (dcs[i] == e);
    if (!active) return;   // uniform across block

    // sA[2]: 1024 chunks each (128 co rows x 8 ci-chunks of 8 bf16), 16 KB each -> 32 KB.
    // sB   : 1792 chunks (1632 live: 6x34 halo rows x 8 ci-chunks; rest dead padding so
    //        staging is a uniform 7 loads/thread), 28 KB, single buffer.
    // Total 60 KB -> 2 blocks/CU (= the register-bound occupancy; no loss).
    __shared__ __align__(16) unsigned short sA[2][1024*8];
    __shared__ __align__(16) unsigned short sB[1792*8];

    int t = threadIdx.x;
    int wave = t >> 6, lane = t & 63;
    int wm = wave >> 1, wn = wave & 1;     // 2x2 wave grid, 64x64 per wave
    int kg = lane >> 4, ln = lane & 15;

    int ph0 = nt * 4;       // padded halo start row
    int co0 = mt * 128;

    floatx4 acc[4][4];
    #pragma unroll
    for (int i = 0; i < 4; ++i)
        #pragma unroll
        for (int j = 0; j < 4; ++j) acc[i][j] = (floatx4)0.0f;

    const unsigned short* xb = xt + ((size_t)b*PH + ph0)*PW*CIN;   // halo base (6x34 rows)
    const unsigned short* wb = wt + (size_t)e*9*COUT*CIN + (size_t)co0*CIN;

    // ---- staging (16 B/lane, lane-linear LDS dest, XOR-swizzled source) ----
    auto stageA = [&](int ck, int sh, int buf) {           // 1024 chunks, 4 loads/thread
        const unsigned short* wsrc = wb + (size_t)sh*COUT*CIN + ck*64;
        #pragma unroll
        for (int k = 0; k < 4; ++k) {
            int c = t + k*256;
            int row = c >> 3, gl = c & 7;
            int gs = gl ^ (row & 7);
            gld_lds16(wsrc + (size_t)row*CIN + gs*8, &sA[buf][c*8]);
        }
    };
    auto stageB = [&](int ck) {                            // 1632 live chunks, 7 loads/thread
        const unsigned short* xsrc = xb + ck*64;
        #pragma unroll
        for (int k = 0; k < 7; ++k) {
            int c = t + k*256;
            int cc = c < 1632 ? c : 1631;  // clamp SOURCE only; dest stays lane-linear (pad)
            int rB = cc >> 3, gl = cc & 7;
            int gs = gl ^ (rB & 7);
            gld_lds16(xsrc + (size_t)rB*CIN + gs*8, &sB[c*8]);
        }
    };

    // ---- frag reads (swizzled); kh = K-half (0: ci 0..31 of chunk, 1: ci 32..63) ----
    short8 a[4], bv[4];
    auto readA = [&](int kh, int ab) {
        #pragma unroll
        for (int im = 0; im < 4; ++im) {
            int row = wm*64 + im*16 + ln;
            int gl = kh*4 + kg;
            int cL = row*8 + (gl ^ (row & 7));
            a[im] = *(const short8*)(&sA[ab][cL*8]);
        }
    };
    auto readB = [&](int kh, int r, int s) {
        #pragma unroll
        for (int in = 0; in < 4; ++in) {
            int n  = wn*64 + in*16 + ln;
            int hl = n >> 5, wl = n & 31;
            int rB = (hl + r)*34 + (wl + s);
            int gl = kh*4 + kg;
            int cL = rB*8 + (gl ^ (rB & 7));
            bv[in] = *(const short8*)(&sB[cL*8]);
        }
    };
    auto mfma16 = [&]() {
        #pragma unroll
        for (int im = 0; im < 4; ++im)
            #pragma unroll
            for (int in = 0; in < 4; ++in)
                acc[im][in] = __builtin_amdgcn_mfma_f32_16x16x32_bf16(bv[in], a[im], acc[im][in], 0, 0, 0);
    };

    // ---- prologue: stage iteration 0 ----
    stageB(0);
    stageA(0, 0, 0);
    __syncthreads();

    // ---- main loop: 4 ci-chunks of 64 x 9 shifts = 36 iterations ----
    for (int ck = 0; ck < 4; ++ck) {
        for (int sh = 0; sh < 9; ++sh) {
            int it = ck*9 + sh;
            int ab = it & 1;
            int r = sh / 3, s = sh - r*3;

            if (sh < 8) {
                stageA(ck, sh + 1, ab ^ 1);
                readA(0, ab); readB(0, r, s); mfma16();
                readA(1, ab); readB(1, r, s); mfma16();
                __syncthreads();   // frag reads done + prefetch DMA drained
            } else {
                // ck boundary: finish K-half 0, read half-1 B frags, fence all waves'
                // sB reads, restage sB (+ next A), then finish half 1.
                readA(0, ab); readB(0, r, s); mfma16();
                readB(1, r, s);
                if (ck < 3) {
                    asm volatile("s_waitcnt lgkmcnt(0)" ::: "memory");
                    __builtin_amdgcn_s_barrier();
                    stageB(ck + 1);
                    stageA(ck + 1, 0, ab ^ 1);
                }
                readA(1, ab); mfma16();
                if (ck < 3) __syncthreads();   // drains restage DMA
            }
        }
    }

    // ---- epilogue: bias + relu.  Layout: col(ln)=co, row(kg*4+rg)=hw ----
    float bias[4];
    #pragma unroll
    for (int im = 0; im < 4; ++im)
        bias[im] = be[e*COUT + co0 + wm*64 + im*16 + ln];
    #pragma unroll
    for (int im = 0; im < 4; ++im)
        #pragma unroll
        for (int in = 0; in < 4; ++in)
            #pragma unroll
            for (int rg = 0; rg < 4; ++rg) {
                float v = acc[im][in][rg] + bias[im];
                acc[im][in][rg] = v > 0.0f ? v : 0.0f;
            }

    // ---- write to every output slot i with dec[i]==e: float4 stores along hw ----
    for (int i = 0; i < 16; ++i) {
        if (dcs[i] != e) continue;
        float* ob = out + (size_t)(i*16 + b)*COUT*HW;
        #pragma unroll
        for (int im = 0; im < 4; ++im) {
            int co = co0 + wm*64 + im*16 + ln;
            float* orow = ob + (size_t)co*HW + nt*128 + wn*64 + kg*4;
            #pragma unroll
            for (int in = 0; in < 4; ++in)
                *(floatx4*)(orow + in*16) = acc[im][in];
        }
    }
}

extern "C" void kernel_launch(void* const* d_in, const int* in_sizes, int n_in,
                              void* d_out, int out_size, void* d_ws, size_t ws_size,
                              hipStream_t stream) {
    const float* x  = (const float*)d_in[0];
    const float* wc = (const float*)d_in[1];
    const float* bc = (const float*)d_in[2];
    const float* we = (const float*)d_in[3];
    const float* be = (const float*)d_in[4];
    float* out = (float*)d_out;

    char* ws = (char*)d_ws;
    int*   dec    = (int*)ws;
    float* pooled = (float*)(ws + 64);
    unsigned short* xt = (unsigned short*)(ws + XT_OFF);
    unsigned short* wt = (unsigned short*)(ws + WT_OFF);

    // Three dispatches.  No memset: prep writes pooled/xt/wt fully; dec written by decide.
    prep_kernel  <<<2176, 256, 0, stream>>>(x, we, xt, wt, pooled);
    decide_kernel<<<1, 128, 0, stream>>>(pooled, wc, bc, dec);
    conv_kernel  <<<2048, 256, 0, stream>>>(xt, wt, be, dec, out);
}